// Round 3
// baseline (147.250 us; speedup 1.0000x reference)
//
#include <hip/hip_runtime.h>
#include <hip/hip_bf16.h>

// Decoder loss: keep-mask (kth-value threshold + local max), BCE coord loss,
// bidirectional NN recolor + L1 rgb loss.
// L=16384 candidates, N=10000 targets, K=8 (collapses to argmin; R1-proven).
// R11: per-pair cost was INVARIANT across R8/R9/R10 restructures (0.164-0.171
// cyc/pair) with VALUBusy 56-65% -> VALU is the loaded pipe and the compiler
// emits ~2x the ideal instruction count (unroll-4 loop overhead). Fix: full-
// chunk specialization with compile-time trip count + unroll 32 so the body
// is exactly {ds_read_b128 offset:imm + 24 VALU} per c-step (3fma+cmp+2sel
// per output). Ideal floor: LDS 12 cyc == VALU 12 CU-cyc per c-step ~12.7us.
// Hard-learned rules for this part:
//   - grid.sync ~40us each (R4), mass __threadfence ~0.1ms+ (R7): NEVER fuse
//     across device-scope ordering. Kernel boundary (~10us) is the cheap sync.
//   - LDS-tiled broadcast scans, not uniform global streams (R5: 7x slower).
//   - bwd & fwd scans are independent -> one dual-role grid, zero sync needed.
//   - fwd scans ALL kept (R7-proven exact); kills k_empty + elist.
//   - per-chunk surrogate argmin + cross-chunk EXACT-d merge key (R1/R3);
//     do not switch to global surrogate argmin (near-tie winner can flip).

#define SCAN_T 256   // threads per block
#define CHUNK  128   // tile elements per y-chunk
typedef unsigned long long ull;

// ---- Kernel 1: init + monotone keys + per-8 local max ----------------------
__global__ __launch_bounds__(256) void k_prep(
    const float* __restrict__ pred, const float* __restrict__ txyz,
    float4* __restrict__ ttile, float4* __restrict__ numden,
    int* __restrict__ zerohit, ull* __restrict__ tmin, ull* __restrict__ fmin,
    unsigned int* __restrict__ key, unsigned char* __restrict__ islm,
    int* __restrict__ counters, float* __restrict__ out, int L, int N) {
  int gidx = blockIdx.x * 256 + threadIdx.x;
  int gsz = (int)gridDim.x * 256;
  for (int i = gidx; i < N; i += gsz) {
    float x = txyz[3*i], y = txyz[3*i+1], z = txyz[3*i+2];
    ttile[i] = make_float4(x, y, z, fmaf(x, x, fmaf(y, y, z * z)));
    tmin[i] = ~0ull;
  }
  for (int i = gidx; i < L; i += gsz) {
    numden[i] = make_float4(0.f, 0.f, 0.f, 0.f);
    zerohit[i] = 0;
    fmin[i] = ~0ull;
  }
  if (gidx < 8) counters[gidx] = 0;
  if (gidx < 2) out[gidx] = 0.f;
  int ngroups = L >> 3;
  for (int g = gidx; g < ngroups; g += gsz) {
    const float4* pv = (const float4*)pred + (size_t)g * 2;
    float4 a = pv[0], b = pv[1];
    float v[8] = {a.x, a.y, a.z, a.w, b.x, b.y, b.z, b.w};
    int bi = 0; float bv = v[0];
    #pragma unroll
    for (int j = 1; j < 8; ++j) if (v[j] > bv) { bv = v[j]; bi = j; }
    unsigned int kk[8];
    ull lmpack = 0ull;
    #pragma unroll
    for (int j = 0; j < 8; ++j) {
      unsigned int fb = __float_as_uint(v[j]);
      unsigned int mk = (fb & 0x80000000u) ? ~fb : (fb | 0x80000000u);
      if (j == bi) { mk = 0xFF800000u; lmpack |= 1ull << (8 * j); }  // +inf
      kk[j] = mk;
    }
    ((uint4*)key)[g*2]   = make_uint4(kk[0], kk[1], kk[2], kk[3]);
    ((uint4*)key)[g*2+1] = make_uint4(kk[4], kk[5], kk[6], kk[7]);
    *(ull*)(islm + (size_t)g * 8) = lmpack;
  }
}

// ---- helper: pick bin containing rank from LDS hist (wave 0) ---------------
__device__ __forceinline__ void select_bin(
    unsigned int* hist, int nb, unsigned int rank,
    unsigned int* sB, unsigned int* sR, int tid) {
  if (tid < 64) {
    int g = nb >> 6;
    unsigned int sum = 0;
    for (int j = 0; j < g; ++j) sum += hist[tid * g + j];
    unsigned int incl = sum;
    for (int o = 1; o < 64; o <<= 1) {
      unsigned int v = __shfl_up(incl, o);
      if (tid >= o) incl += v;
    }
    unsigned int excl = incl - sum;
    bool cond = (rank >= excl) && (rank < incl);
    unsigned long long bal = __ballot(cond);
    int first = __ffsll((long long)bal) - 1;
    if (tid == first) {
      unsigned int r = rank - excl, cum = 0;
      for (int j = 0; j < g; ++j) {
        unsigned int c = hist[tid * g + j];
        if (r < cum + c) { *sB = (unsigned int)(tid * g + j); *sR = r - cum; break; }
        cum += c;
      }
    }
  }
}

// ---- Kernel 2: exact rank select, self-contained (1 block, 3 sweeps) -------
__global__ __launch_bounds__(256) void k_sel(
    const unsigned int* __restrict__ key, const int* __restrict__ pnum_p,
    float* __restrict__ thr_out, int L) {
  __shared__ unsigned int hist[2048];
  __shared__ unsigned int sB, sR;
  int tid = threadIdx.x;
  unsigned int rank = (unsigned int)(L - pnum_p[0] - 1);
  const uint4* k4 = (const uint4*)key;
  int n4 = L >> 2;
  for (int b = tid; b < 2048; b += 256) hist[b] = 0u;
  __syncthreads();
  for (int i = tid; i < n4; i += 256) {
    uint4 v = k4[i];
    atomicAdd(&hist[v.x >> 21], 1u); atomicAdd(&hist[v.y >> 21], 1u);
    atomicAdd(&hist[v.z >> 21], 1u); atomicAdd(&hist[v.w >> 21], 1u);
  }
  __syncthreads();
  select_bin(hist, 2048, rank, &sB, &sR, tid);
  __syncthreads();
  unsigned int B1 = sB, R1 = sR;
  for (int b = tid; b < 2048; b += 256) hist[b] = 0u;
  __syncthreads();
  for (int i = tid; i < n4; i += 256) {
    uint4 v = k4[i];
    if ((v.x >> 21) == B1) atomicAdd(&hist[(v.x >> 10) & 2047u], 1u);
    if ((v.y >> 21) == B1) atomicAdd(&hist[(v.y >> 10) & 2047u], 1u);
    if ((v.z >> 21) == B1) atomicAdd(&hist[(v.z >> 10) & 2047u], 1u);
    if ((v.w >> 21) == B1) atomicAdd(&hist[(v.w >> 10) & 2047u], 1u);
  }
  __syncthreads();
  select_bin(hist, 2048, R1, &sB, &sR, tid);
  __syncthreads();
  unsigned int B2 = sB, R2 = sR;
  for (int b = tid; b < 1024; b += 256) hist[b] = 0u;
  __syncthreads();
  unsigned int top22 = (B1 << 11) | B2;
  for (int i = tid; i < n4; i += 256) {
    uint4 v = k4[i];
    if ((v.x >> 10) == top22) atomicAdd(&hist[v.x & 1023u], 1u);
    if ((v.y >> 10) == top22) atomicAdd(&hist[v.y & 1023u], 1u);
    if ((v.z >> 10) == top22) atomicAdd(&hist[v.z & 1023u], 1u);
    if ((v.w >> 10) == top22) atomicAdd(&hist[v.w & 1023u], 1u);
  }
  __syncthreads();
  select_bin(hist, 1024, R2, &sB, &sR, tid);
  __syncthreads();
  if (tid == 0) {
    unsigned int fkey = (B1 << 21) | (B2 << 10) | sB;
    unsigned int fb = (fkey & 0x80000000u) ? (fkey & 0x7FFFFFFFu) : ~fkey;
    thr_out[0] = __uint_as_float(fb);
  }
}

// ---- Kernel 3: keep mask + compaction + BCE reduce -------------------------
__global__ __launch_bounds__(256) void k_keepc(
    const float* __restrict__ pred, const unsigned char* __restrict__ islm,
    const float* __restrict__ thr_p, const float* __restrict__ cxyz,
    const int* __restrict__ ktgt, int* __restrict__ keep,
    float4* __restrict__ klist, int* __restrict__ kidx,
    int* __restrict__ counters, float* __restrict__ out, int L) {
  int i = blockIdx.x * 256 + threadIdx.x;
  float thr = thr_p[0];
  float term = 0.f;
  if (i < L) {
    float p = pred[i];
    bool kp = (p > thr) || islm[i];
    keep[i] = kp ? 1 : 0;
    if (kp) {
      int pos = atomicAdd(&counters[0], 1);   // order irrelevant (no ties)
      float x = cxyz[3*i], y = cxyz[3*i+1], z = cxyz[3*i+2];
      klist[pos] = make_float4(x, y, z, fmaf(x, x, fmaf(y, y, z * z)));
      kidx[pos] = i;
    }
    float t = (float)ktgt[i];
    term = fmaxf(p, 0.f) - p * t + log1pf(expf(-fabsf(p)));
  }
  for (int o = 32; o > 0; o >>= 1) term += __shfl_down(term, o);
  if ((threadIdx.x & 63) == 0) atomicAdd(&out[0], term);
}

// ---- hot inner scan: 4 outputs/thread over one LDS tile --------------------
// Per c-step target codegen: 1 ds_read_b128 (imm offset) + 24 VALU
// (per j: 3 v_fma + v_cmp + v_min + v_cndmask). c stays uniform (SGPR),
// legal as the single SGPR operand of the bpos cndmask. Strict < keeps
// first-min tie-break (matches R10 semantics).
__device__ __forceinline__ void scan_tile(
    const float4* tile, int cnt,
    const float* nx, const float* ny, const float* nz,
    float* best, int* bpos) {
  if (cnt == CHUNK) {
    #pragma unroll 32
    for (int c = 0; c < CHUNK; ++c) {
      float4 cd = tile[c];
      #pragma unroll
      for (int j = 0; j < 4; ++j) {
        float d = fmaf(nx[j], cd.x, cd.w);
        d = fmaf(ny[j], cd.y, d);
        d = fmaf(nz[j], cd.z, d);
        bool lt = d < best[j];
        bpos[j] = lt ? c : bpos[j];
        best[j] = lt ? d : best[j];
      }
    }
  } else {
    #pragma unroll 4
    for (int c = 0; c < cnt; ++c) {
      float4 cd = tile[c];
      #pragma unroll
      for (int j = 0; j < 4; ++j) {
        float d = fmaf(nx[j], cd.x, cd.w);
        d = fmaf(ny[j], cd.y, d);
        d = fmaf(nz[j], cd.z, d);
        bool lt = d < best[j];
        bpos[j] = lt ? c : bpos[j];
        best[j] = lt ? d : best[j];
      }
    }
  }
}

// ---- Kernel 4: dual-role scan (bwd y<YB, fwd y>=YB), LDS-tiled -------------
__global__ __launch_bounds__(SCAN_T) void k_scan2(
    const float* __restrict__ txyz, const float4* __restrict__ klist,
    const int* __restrict__ kidx, const float4* __restrict__ ttile,
    const int* __restrict__ counters, ull* __restrict__ tmin,
    ull* __restrict__ fmin, int L, int N, int YB) {
  __shared__ float4 tile[CHUNK];
  int tid = threadIdx.x, x = blockIdx.x, y = blockIdx.y;
  int kc = counters[0];

  if (y < YB) {
    // ---- backward: targets x*1024.. (4/thread) vs kept chunk y (128) ------
    int c0 = y * CHUNK;
    if (x * 1024 >= N || c0 >= kc) return;   // uniform early-exit
    int cnt = min(CHUNK, kc - c0);
    if (tid < cnt) tile[tid] = klist[c0 + tid];
    __syncthreads();
    int tb = x * 1024 + tid;
    float ntx[4], nty[4], ntz[4], best[4];
    int bpos[4];
    bool act[4];
    #pragma unroll
    for (int j = 0; j < 4; ++j) {
      int t = tb + 256 * j;
      act[j] = t < N;
      float tx = 0.f, ty = 0.f, tz = 0.f;
      if (act[j]) { tx = txyz[3*t]; ty = txyz[3*t+1]; tz = txyz[3*t+2]; }
      ntx[j] = -2.f * tx; nty[j] = -2.f * ty; ntz[j] = -2.f * tz;
      best[j] = 3e38f; bpos[j] = 0;
    }
    // monotone surrogate |c|^2 - 2 t.c (argmin-equiv to |t-c|^2)
    scan_tile(tile, cnt, ntx, nty, ntz, best, bpos);
    #pragma unroll
    for (int j = 0; j < 4; ++j) {
      if (act[j]) {
        int p = c0 + bpos[j];
        float4 cd = klist[p];
        float tx = -0.5f * ntx[j], ty = -0.5f * nty[j], tz = -0.5f * ntz[j];
        float dx = tx - cd.x, dy = ty - cd.y, dz = tz - cd.z;
        float dtrue = fmaf(dx, dx, fmaf(dy, dy, dz * dz));  // exact (R1)
        ull pack = ((ull)__float_as_uint(dtrue) << 32) | (unsigned int)kidx[p];
        atomicMin(&tmin[tb + 256 * j], pack);
      }
    }
  } else {
    // ---- forward: kept cands x*1024.. (4/thread) vs target chunk (128) ----
    int t0 = (y - YB) * CHUNK;
    if (x * 1024 >= kc || t0 >= N) return;   // uniform early-exit
    int tcnt = min(CHUNK, N - t0);
    if (tid < tcnt) tile[tid] = ttile[t0 + tid];
    __syncthreads();
    int eb = x * 1024 + tid;
    float ncx[4], ncy[4], ncz[4], c2[4], best[4];
    int bpos[4], li[4];
    bool act[4];
    #pragma unroll
    for (int j = 0; j < 4; ++j) {
      int e = eb + 256 * j;
      act[j] = e < kc;
      float cx = 0.f, cy = 0.f, cz = 0.f;
      c2[j] = 0.f; li[j] = 0;
      if (act[j]) {
        float4 cd = klist[e];
        cx = cd.x; cy = cd.y; cz = cd.z; c2[j] = cd.w;
        li[j] = kidx[e];
      }
      ncx[j] = -2.f * cx; ncy[j] = -2.f * cy; ncz[j] = -2.f * cz;
      best[j] = 3e38f; bpos[j] = 0;
    }
    scan_tile(tile, tcnt, ncx, ncy, ncz, best, bpos);
    #pragma unroll
    for (int j = 0; j < 4; ++j) {
      if (act[j]) {
        float dkey = fmaxf(best[j] + c2[j], 0.f);  // consistent merge key (R3)
        ull pack = ((ull)__float_as_uint(dkey) << 32) |
                   (unsigned int)(t0 + bpos[j]);
        atomicMin(&fmin[li[j]], pack);
      }
    }
  }
}

// ---- Kernel 5: scatter weighted colors into num/den ------------------------
__global__ __launch_bounds__(256) void k_scatter(
    const float* __restrict__ trgb, const ull* __restrict__ tmin,
    float4* __restrict__ numden, int* __restrict__ zerohit,
    float4* __restrict__ zcolor, int N) {
  int t = blockIdx.x * 256 + threadIdx.x;
  if (t >= N) return;
  ull pack = tmin[t];
  float d = __uint_as_float((unsigned int)(pack >> 32));
  int idx = (int)(pack & 0xFFFFFFFFull);
  float r = trgb[3*t], g = trgb[3*t+1], b = trgb[3*t+2];
  if (d == 0.0f) {
    zerohit[idx] = 1;
    zcolor[idx] = make_float4(r, g, b, 0.f);
  } else {
    float w = 1.0f / sqrtf(fmaxf(d, 1e-30f));
    atomicAdd(&numden[idx].x, r * w);
    atomicAdd(&numden[idx].y, g * w);
    atomicAdd(&numden[idx].z, b * w);
    atomicAdd(&numden[idx].w, w);
  }
}

// ---- Kernel 6: final recolor select + L1 reduce ----------------------------
__global__ __launch_bounds__(256) void k_loss(
    const float* __restrict__ crgb, const float* __restrict__ trgb,
    const int* __restrict__ keep, const float4* __restrict__ numden,
    const int* __restrict__ zerohit, const float4* __restrict__ zcolor,
    const ull* __restrict__ fmin, float* __restrict__ out, int L) {
  int l = blockIdx.x * 256 + threadIdx.x;
  float loss = 0.f;
  if (l < L && keep[l]) {
    float rr, rg, rb;
    if (zerohit[l]) {
      float4 z = zcolor[l]; rr = z.x; rg = z.y; rb = z.z;
    } else {
      float4 nd = numden[l];
      if (nd.w != 0.f) { rr = nd.x / nd.w; rg = nd.y / nd.w; rb = nd.z / nd.w; }
      else {
        int ti = (int)(fmin[l] & 0xFFFFFFFFull);
        rr = trgb[3*ti]; rg = trgb[3*ti+1]; rb = trgb[3*ti+2];
      }
    }
    float sr = crgb[3*l]*255.f, sg = crgb[3*l+1]*255.f, sb = crgb[3*l+2]*255.f;
    loss = fabsf(sr - rr) + fabsf(sg - rg) + fabsf(sb - rb);
  }
  for (int o = 32; o > 0; o >>= 1) loss += __shfl_down(loss, o);
  if ((threadIdx.x & 63) == 0) atomicAdd(&out[1], loss);
}

extern "C" void kernel_launch(void* const* d_in, const int* in_sizes, int n_in,
                              void* d_out, int out_size, void* d_ws, size_t ws_size,
                              hipStream_t stream) {
  const float* pred = (const float*)d_in[0];
  const float* cxyz = (const float*)d_in[1];
  const float* crgb = (const float*)d_in[2];
  const float* txyz = (const float*)d_in[3];
  const float* trgb = (const float*)d_in[4];
  const int*   ktgt = (const int*)d_in[5];
  const int*   pnum = (const int*)d_in[6];
  int L = in_sizes[0];
  int N = in_sizes[3] / 3;

  // workspace layout: 16B arrays first, then 8B, 4B, bytes
  char* ws = (char*)d_ws;
  size_t off = 0;
  float4* klist  = (float4*)(ws + off);   off += (size_t)L * 16;
  float4* ttile  = (float4*)(ws + off);   off += (size_t)((N + 3) & ~3) * 16;
  float4* numden = (float4*)(ws + off);   off += (size_t)L * 16;
  float4* zcolor = (float4*)(ws + off);   off += (size_t)L * 16;
  unsigned int* key = (unsigned int*)(ws + off); off += (size_t)L * 4;  // uint4-aligned
  ull* tmin      = (ull*)(ws + off);      off += (size_t)((N + 1) & ~1) * 8;
  ull* fmin      = (ull*)(ws + off);      off += (size_t)L * 8;
  int* keep      = (int*)(ws + off);      off += (size_t)L * 4;
  int* kidx      = (int*)(ws + off);      off += (size_t)L * 4;
  int* zerohit   = (int*)(ws + off);      off += (size_t)L * 4;
  float* thr_slot = (float*)(ws + off);   off += 16;
  int* counters  = (int*)(ws + off);      off += 256;   // [0]=kcount
  unsigned char* islm = (unsigned char*)(ws + off); off += ((size_t)L + 15) & ~15ull;
  float* out = (float*)d_out;

  int nbL = (L + 255) / 256;   // 64
  int nbN = (N + 255) / 256;   // 40
  int mx = max(L, N);

  k_prep<<<(mx + 255) / 256, 256, 0, stream>>>(
      pred, txyz, ttile, numden, zerohit, tmin, fmin, key, islm, counters, out, L, N);

  k_sel<<<1, 256, 0, stream>>>(key, pnum, thr_slot, L);

  k_keepc<<<nbL, 256, 0, stream>>>(
      pred, islm, thr_slot, cxyz, ktgt, keep, klist, kidx, counters, out, L);

  // grid: x covers 1024 outputs/block (4/thread); y = 128-chunks.
  int gx = (mx + 1023) / 1024;               // 16
  int YB = (L + CHUNK - 1) / CHUNK;          // 128 kept-chunks (exit at kc)
  int YF = (N + CHUNK - 1) / CHUNK;          // 79 target-chunks
  dim3 gs(gx, YB + YF);
  k_scan2<<<gs, SCAN_T, 0, stream>>>(
      txyz, klist, kidx, ttile, counters, tmin, fmin, L, N, YB);

  k_scatter<<<nbN, 256, 0, stream>>>(trgb, tmin, numden, zerohit, zcolor, N);

  k_loss<<<nbL, 256, 0, stream>>>(
      crgb, trgb, keep, numden, zerohit, zcolor, fmin, out, L);
}

// Round 4
// 132.379 us; speedup vs baseline: 1.1123x; 1.1123x over previous
//
#include <hip/hip_runtime.h>
#include <hip/hip_bf16.h>

// Decoder loss: keep-mask (kth-value threshold + local max), BCE coord loss,
// bidirectional NN recolor + L1 rgb loss.
// L=16384 candidates, N=10000 targets, K=8 (collapses to argmin; R1-proven).
// R12: totals across R8-R11 = k_scan2 + ~97us INVARIANT -> the non-scan
// budget (5 small kernels + boundaries, ~10us each; k_sel alone ~10-15us as
// a single-block 3x global-sweep) is the real target. Fuse prep+sel: last
// block computes keys in LDS (64KB+8KB hist) + islm and 3-sweep selects from
// LDS; 32 init blocks run concurrently. 6->5 dispatches, keys never hit HBM.
// k_scan2 reverted to the R10 body (43.0us proven; R11's unroll-32 variant
// regressed to 48.7 - codegen, not instr count, rules that loop).
// Hard-learned rules for this part:
//   - grid.sync ~40us each (R4), mass __threadfence ~0.1ms+ (R7): NEVER fuse
//     across device-scope ordering. Kernel boundary (~10us) is the cheap sync.
//   - LDS-tiled broadcast scans, not uniform global streams (R5: 7x slower).
//   - bwd & fwd scans are independent -> one dual-role grid, zero sync needed.
//   - fwd scans ALL kept (R7-proven exact); kills k_empty + elist.
//   - per-chunk surrogate argmin + cross-chunk EXACT-d merge key (R1/R3);
//     do not switch to global surrogate argmin (near-tie winner can flip).
//   - k_scan2 inner loop: duration/pair is invariant to VALU count, LDS
//     count, occupancy (R8-R11). Don't touch without a disasm-level model.

#define SCAN_T 256   // threads per block (scan)
#define CHUNK  128   // tile elements per y-chunk
typedef unsigned long long ull;

// ---- helper: pick bin containing rank from LDS hist (wave 0) ---------------
__device__ __forceinline__ void select_bin(
    unsigned int* hist, int nb, unsigned int rank,
    unsigned int* sB, unsigned int* sR, int tid) {
  if (tid < 64) {
    int g = nb >> 6;
    unsigned int sum = 0;
    for (int j = 0; j < g; ++j) sum += hist[tid * g + j];
    unsigned int incl = sum;
    for (int o = 1; o < 64; o <<= 1) {
      unsigned int v = __shfl_up(incl, o);
      if (tid >= o) incl += v;
    }
    unsigned int excl = incl - sum;
    bool cond = (rank >= excl) && (rank < incl);
    unsigned long long bal = __ballot(cond);
    int first = __ffsll((long long)bal) - 1;
    if (tid == first) {
      unsigned int r = rank - excl, cum = 0;
      for (int j = 0; j < g; ++j) {
        unsigned int c = hist[tid * g + j];
        if (r < cum + c) { *sB = (unsigned int)(tid * g + j); *sR = r - cum; break; }
        cum += c;
      }
    }
  }
}

// ---- Kernel 1: fused init + keys + exact rank select -----------------------
// Blocks 0..IB-1: array init (BW-trivial). Block IB: compute monotone keys
// into LDS + islm to global, then 3-sweep radix select entirely from LDS.
// Assumes L <= 16384 (fixed by problem setup).
__global__ __launch_bounds__(512) void k_init_sel(
    const float* __restrict__ pred, const float* __restrict__ txyz,
    const int* __restrict__ pnum_p,
    float4* __restrict__ ttile, float4* __restrict__ numden,
    int* __restrict__ zerohit, ull* __restrict__ tmin, ull* __restrict__ fmin,
    unsigned char* __restrict__ islm, int* __restrict__ counters,
    float* __restrict__ out, float* __restrict__ thr_out,
    int L, int N, int IB) {
  __shared__ unsigned int skey[16384];
  __shared__ unsigned int hist[2048];
  __shared__ unsigned int sB, sR;
  int tid = threadIdx.x;

  if ((int)blockIdx.x < IB) {
    // ---- init role --------------------------------------------------------
    int gidx = blockIdx.x * 512 + tid;
    int gsz = IB * 512;
    for (int i = gidx; i < N; i += gsz) {
      float x = txyz[3*i], y = txyz[3*i+1], z = txyz[3*i+2];
      ttile[i] = make_float4(x, y, z, fmaf(x, x, fmaf(y, y, z * z)));
      tmin[i] = ~0ull;
    }
    for (int i = gidx; i < L; i += gsz) {
      numden[i] = make_float4(0.f, 0.f, 0.f, 0.f);
      zerohit[i] = 0;
      fmin[i] = ~0ull;
    }
    if (gidx < 8) counters[gidx] = 0;
    if (gidx < 2) out[gidx] = 0.f;
    return;
  }

  // ---- selector role ------------------------------------------------------
  // phase A: monotone keys (LDS) + per-8 local max (global islm)
  int ngroups = L >> 3;
  for (int g = tid; g < ngroups; g += 512) {
    const float4* pv = (const float4*)pred + (size_t)g * 2;
    float4 a = pv[0], b = pv[1];
    float v[8] = {a.x, a.y, a.z, a.w, b.x, b.y, b.z, b.w};
    int bi = 0; float bv = v[0];
    #pragma unroll
    for (int j = 1; j < 8; ++j) if (v[j] > bv) { bv = v[j]; bi = j; }
    ull lmpack = 0ull;
    #pragma unroll
    for (int j = 0; j < 8; ++j) {
      unsigned int fb = __float_as_uint(v[j]);
      unsigned int mk = (fb & 0x80000000u) ? ~fb : (fb | 0x80000000u);
      if (j == bi) { mk = 0xFF800000u; lmpack |= 1ull << (8 * j); }  // +inf
      skey[g * 8 + j] = mk;
    }
    *(ull*)(islm + (size_t)g * 8) = lmpack;
  }
  __syncthreads();

  // phase B: 3-sweep radix select over LDS keys
  unsigned int rank = (unsigned int)(L - pnum_p[0] - 1);
  const uint4* s4 = (const uint4*)skey;
  int n4 = L >> 2;
  for (int b = tid; b < 2048; b += 512) hist[b] = 0u;
  __syncthreads();
  for (int i = tid; i < n4; i += 512) {
    uint4 v = s4[i];
    atomicAdd(&hist[v.x >> 21], 1u); atomicAdd(&hist[v.y >> 21], 1u);
    atomicAdd(&hist[v.z >> 21], 1u); atomicAdd(&hist[v.w >> 21], 1u);
  }
  __syncthreads();
  select_bin(hist, 2048, rank, &sB, &sR, tid);
  __syncthreads();
  unsigned int B1 = sB, R1 = sR;
  for (int b = tid; b < 2048; b += 512) hist[b] = 0u;
  __syncthreads();
  for (int i = tid; i < n4; i += 512) {
    uint4 v = s4[i];
    if ((v.x >> 21) == B1) atomicAdd(&hist[(v.x >> 10) & 2047u], 1u);
    if ((v.y >> 21) == B1) atomicAdd(&hist[(v.y >> 10) & 2047u], 1u);
    if ((v.z >> 21) == B1) atomicAdd(&hist[(v.z >> 10) & 2047u], 1u);
    if ((v.w >> 21) == B1) atomicAdd(&hist[(v.w >> 10) & 2047u], 1u);
  }
  __syncthreads();
  select_bin(hist, 2048, R1, &sB, &sR, tid);
  __syncthreads();
  unsigned int B2 = sB, R2 = sR;
  for (int b = tid; b < 1024; b += 512) hist[b] = 0u;
  __syncthreads();
  unsigned int top22 = (B1 << 11) | B2;
  for (int i = tid; i < n4; i += 512) {
    uint4 v = s4[i];
    if ((v.x >> 10) == top22) atomicAdd(&hist[v.x & 1023u], 1u);
    if ((v.y >> 10) == top22) atomicAdd(&hist[v.y & 1023u], 1u);
    if ((v.z >> 10) == top22) atomicAdd(&hist[v.z & 1023u], 1u);
    if ((v.w >> 10) == top22) atomicAdd(&hist[v.w & 1023u], 1u);
  }
  __syncthreads();
  select_bin(hist, 1024, R2, &sB, &sR, tid);
  __syncthreads();
  if (tid == 0) {
    unsigned int fkey = (B1 << 21) | (B2 << 10) | sB;
    unsigned int fb = (fkey & 0x80000000u) ? (fkey & 0x7FFFFFFFu) : ~fkey;
    thr_out[0] = __uint_as_float(fb);
  }
}

// ---- Kernel 2: keep mask + compaction + BCE reduce -------------------------
__global__ __launch_bounds__(256) void k_keepc(
    const float* __restrict__ pred, const unsigned char* __restrict__ islm,
    const float* __restrict__ thr_p, const float* __restrict__ cxyz,
    const int* __restrict__ ktgt, int* __restrict__ keep,
    float4* __restrict__ klist, int* __restrict__ kidx,
    int* __restrict__ counters, float* __restrict__ out, int L) {
  int i = blockIdx.x * 256 + threadIdx.x;
  float thr = thr_p[0];
  float term = 0.f;
  if (i < L) {
    float p = pred[i];
    bool kp = (p > thr) || islm[i];
    keep[i] = kp ? 1 : 0;
    if (kp) {
      int pos = atomicAdd(&counters[0], 1);   // order irrelevant (no ties)
      float x = cxyz[3*i], y = cxyz[3*i+1], z = cxyz[3*i+2];
      klist[pos] = make_float4(x, y, z, fmaf(x, x, fmaf(y, y, z * z)));
      kidx[pos] = i;
    }
    float t = (float)ktgt[i];
    term = fmaxf(p, 0.f) - p * t + log1pf(expf(-fabsf(p)));
  }
  for (int o = 32; o > 0; o >>= 1) term += __shfl_down(term, o);
  if ((threadIdx.x & 63) == 0) atomicAdd(&out[0], term);
}

// ---- Kernel 3: dual-role scan (bwd y<YB, fwd y>=YB), LDS-tiled -------------
// R10 body (proven 43.0us): 4 outputs/thread, CHUNK=128, ~1270 blocks.
__global__ __launch_bounds__(SCAN_T) void k_scan2(
    const float* __restrict__ txyz, const float4* __restrict__ klist,
    const int* __restrict__ kidx, const float4* __restrict__ ttile,
    const int* __restrict__ counters, ull* __restrict__ tmin,
    ull* __restrict__ fmin, int L, int N, int YB) {
  __shared__ float4 tile[CHUNK];
  int tid = threadIdx.x, x = blockIdx.x, y = blockIdx.y;
  int kc = counters[0];

  if (y < YB) {
    // ---- backward: targets x*1024.. (4/thread) vs kept chunk y (128) ------
    int c0 = y * CHUNK;
    if (x * 1024 >= N || c0 >= kc) return;   // uniform early-exit
    int cnt = min(CHUNK, kc - c0);
    if (tid < cnt) tile[tid] = klist[c0 + tid];
    __syncthreads();
    int tb = x * 1024 + tid;
    float ntx[4], nty[4], ntz[4], best[4];
    int bpos[4];
    bool act[4];
    #pragma unroll
    for (int j = 0; j < 4; ++j) {
      int t = tb + 256 * j;
      act[j] = t < N;
      float tx = 0.f, ty = 0.f, tz = 0.f;
      if (act[j]) { tx = txyz[3*t]; ty = txyz[3*t+1]; tz = txyz[3*t+2]; }
      ntx[j] = -2.f * tx; nty[j] = -2.f * ty; ntz[j] = -2.f * tz;
      best[j] = 3e38f; bpos[j] = 0;
    }
    #pragma unroll 4
    for (int c = 0; c < cnt; ++c) {
      float4 cd = tile[c];
      #pragma unroll
      for (int j = 0; j < 4; ++j) {
        // monotone surrogate |c|^2 - 2 t.c (argmin-equiv to |t-c|^2)
        float d = fmaf(ntx[j], cd.x, cd.w);
        d = fmaf(nty[j], cd.y, d);
        d = fmaf(ntz[j], cd.z, d);
        if (d < best[j]) { best[j] = d; bpos[j] = c; }
      }
    }
    #pragma unroll
    for (int j = 0; j < 4; ++j) {
      if (act[j]) {
        int p = c0 + bpos[j];
        float4 cd = klist[p];
        float tx = -0.5f * ntx[j], ty = -0.5f * nty[j], tz = -0.5f * ntz[j];
        float dx = tx - cd.x, dy = ty - cd.y, dz = tz - cd.z;
        float dtrue = fmaf(dx, dx, fmaf(dy, dy, dz * dz));  // exact (R1)
        ull pack = ((ull)__float_as_uint(dtrue) << 32) | (unsigned int)kidx[p];
        atomicMin(&tmin[tb + 256 * j], pack);
      }
    }
  } else {
    // ---- forward: kept cands x*1024.. (4/thread) vs target chunk (128) ----
    int t0 = (y - YB) * CHUNK;
    if (x * 1024 >= kc || t0 >= N) return;   // uniform early-exit
    int tcnt = min(CHUNK, N - t0);
    if (tid < tcnt) tile[tid] = ttile[t0 + tid];
    __syncthreads();
    int eb = x * 1024 + tid;
    float ncx[4], ncy[4], ncz[4], c2[4], best[4];
    int bpos[4], li[4];
    bool act[4];
    #pragma unroll
    for (int j = 0; j < 4; ++j) {
      int e = eb + 256 * j;
      act[j] = e < kc;
      float cx = 0.f, cy = 0.f, cz = 0.f;
      c2[j] = 0.f; li[j] = 0;
      if (act[j]) {
        float4 cd = klist[e];
        cx = cd.x; cy = cd.y; cz = cd.z; c2[j] = cd.w;
        li[j] = kidx[e];
      }
      ncx[j] = -2.f * cx; ncy[j] = -2.f * cy; ncz[j] = -2.f * cz;
      best[j] = 3e38f; bpos[j] = 0;
    }
    #pragma unroll 4
    for (int c = 0; c < tcnt; ++c) {
      float4 td = tile[c];
      #pragma unroll
      for (int j = 0; j < 4; ++j) {
        float d = fmaf(ncx[j], td.x, td.w);
        d = fmaf(ncy[j], td.y, d);
        d = fmaf(ncz[j], td.z, d);
        if (d < best[j]) { best[j] = d; bpos[j] = c; }
      }
    }
    #pragma unroll
    for (int j = 0; j < 4; ++j) {
      if (act[j]) {
        float dkey = fmaxf(best[j] + c2[j], 0.f);  // consistent merge key (R3)
        ull pack = ((ull)__float_as_uint(dkey) << 32) |
                   (unsigned int)(t0 + bpos[j]);
        atomicMin(&fmin[li[j]], pack);
      }
    }
  }
}

// ---- Kernel 4: scatter weighted colors into num/den ------------------------
__global__ __launch_bounds__(256) void k_scatter(
    const float* __restrict__ trgb, const ull* __restrict__ tmin,
    float4* __restrict__ numden, int* __restrict__ zerohit,
    float4* __restrict__ zcolor, int N) {
  int t = blockIdx.x * 256 + threadIdx.x;
  if (t >= N) return;
  ull pack = tmin[t];
  float d = __uint_as_float((unsigned int)(pack >> 32));
  int idx = (int)(pack & 0xFFFFFFFFull);
  float r = trgb[3*t], g = trgb[3*t+1], b = trgb[3*t+2];
  if (d == 0.0f) {
    zerohit[idx] = 1;
    zcolor[idx] = make_float4(r, g, b, 0.f);
  } else {
    float w = 1.0f / sqrtf(fmaxf(d, 1e-30f));
    atomicAdd(&numden[idx].x, r * w);
    atomicAdd(&numden[idx].y, g * w);
    atomicAdd(&numden[idx].z, b * w);
    atomicAdd(&numden[idx].w, w);
  }
}

// ---- Kernel 5: final recolor select + L1 reduce ----------------------------
__global__ __launch_bounds__(256) void k_loss(
    const float* __restrict__ crgb, const float* __restrict__ trgb,
    const int* __restrict__ keep, const float4* __restrict__ numden,
    const int* __restrict__ zerohit, const float4* __restrict__ zcolor,
    const ull* __restrict__ fmin, float* __restrict__ out, int L) {
  int l = blockIdx.x * 256 + threadIdx.x;
  float loss = 0.f;
  if (l < L && keep[l]) {
    float rr, rg, rb;
    if (zerohit[l]) {
      float4 z = zcolor[l]; rr = z.x; rg = z.y; rb = z.z;
    } else {
      float4 nd = numden[l];
      if (nd.w != 0.f) { rr = nd.x / nd.w; rg = nd.y / nd.w; rb = nd.z / nd.w; }
      else {
        int ti = (int)(fmin[l] & 0xFFFFFFFFull);
        rr = trgb[3*ti]; rg = trgb[3*ti+1]; rb = trgb[3*ti+2];
      }
    }
    float sr = crgb[3*l]*255.f, sg = crgb[3*l+1]*255.f, sb = crgb[3*l+2]*255.f;
    loss = fabsf(sr - rr) + fabsf(sg - rg) + fabsf(sb - rb);
  }
  for (int o = 32; o > 0; o >>= 1) loss += __shfl_down(loss, o);
  if ((threadIdx.x & 63) == 0) atomicAdd(&out[1], loss);
}

extern "C" void kernel_launch(void* const* d_in, const int* in_sizes, int n_in,
                              void* d_out, int out_size, void* d_ws, size_t ws_size,
                              hipStream_t stream) {
  const float* pred = (const float*)d_in[0];
  const float* cxyz = (const float*)d_in[1];
  const float* crgb = (const float*)d_in[2];
  const float* txyz = (const float*)d_in[3];
  const float* trgb = (const float*)d_in[4];
  const int*   ktgt = (const int*)d_in[5];
  const int*   pnum = (const int*)d_in[6];
  int L = in_sizes[0];
  int N = in_sizes[3] / 3;

  // workspace layout: 16B arrays first, then 8B, 4B, bytes
  char* ws = (char*)d_ws;
  size_t off = 0;
  float4* klist  = (float4*)(ws + off);   off += (size_t)L * 16;
  float4* ttile  = (float4*)(ws + off);   off += (size_t)((N + 3) & ~3) * 16;
  float4* numden = (float4*)(ws + off);   off += (size_t)L * 16;
  float4* zcolor = (float4*)(ws + off);   off += (size_t)L * 16;
  ull* tmin      = (ull*)(ws + off);      off += (size_t)((N + 1) & ~1) * 8;
  ull* fmin      = (ull*)(ws + off);      off += (size_t)L * 8;
  int* keep      = (int*)(ws + off);      off += (size_t)L * 4;
  int* kidx      = (int*)(ws + off);      off += (size_t)L * 4;
  int* zerohit   = (int*)(ws + off);      off += (size_t)L * 4;
  float* thr_slot = (float*)(ws + off);   off += 16;
  int* counters  = (int*)(ws + off);      off += 256;   // [0]=kcount
  unsigned char* islm = (unsigned char*)(ws + off); off += ((size_t)L + 15) & ~15ull;
  float* out = (float*)d_out;

  int nbL = (L + 255) / 256;   // 64
  int nbN = (N + 255) / 256;   // 40
  int mx = max(L, N);

  // Kernel 1: fused init + keys + select. Blocks 0..IB-1 init, block IB sels.
  int IB = (mx + 511) / 512;   // 32
  k_init_sel<<<IB + 1, 512, 0, stream>>>(
      pred, txyz, pnum, ttile, numden, zerohit, tmin, fmin, islm, counters,
      out, thr_slot, L, N, IB);

  k_keepc<<<nbL, 256, 0, stream>>>(
      pred, islm, thr_slot, cxyz, ktgt, keep, klist, kidx, counters, out, L);

  // grid: x covers 1024 outputs/block (4/thread); y = 128-chunks.
  int gx = (mx + 1023) / 1024;               // 16
  int YB = (L + CHUNK - 1) / CHUNK;          // 128 kept-chunks (exit at kc)
  int YF = (N + CHUNK - 1) / CHUNK;          // 79 target-chunks
  dim3 gs(gx, YB + YF);
  k_scan2<<<gs, SCAN_T, 0, stream>>>(
      txyz, klist, kidx, ttile, counters, tmin, fmin, L, N, YB);

  k_scatter<<<nbN, 256, 0, stream>>>(trgb, tmin, numden, zerohit, zcolor, N);

  k_loss<<<nbL, 256, 0, stream>>>(
      crgb, trgb, keep, numden, zerohit, zcolor, fmin, out, L);
}